// Round 1
// baseline (1184.644 us; speedup 1.0000x reference)
//
#include <hip/hip_runtime.h>

#define NEG_SLOPE 0.2f
#define GAT_EPS 1e-16f

// ---- monotone float <-> unsigned mapping for atomicMax on floats ----
__device__ __forceinline__ unsigned flipf(float f) {
  unsigned b = __float_as_uint(f);
  return (b & 0x80000000u) ? ~b : (b | 0x80000000u);
}
__device__ __forceinline__ float unflipf(unsigned u) {
  unsigned b = (u & 0x80000000u) ? (u ^ 0x80000000u) : ~u;
  return __uint_as_float(b);
}

// ---- GEMM1: h1 = x @ W1 (128 -> 64), fused alpha_src/alpha_dst ----
__global__ __launch_bounds__(256) void gemm1_kernel(
    const float* __restrict__ x, const float* __restrict__ W1,
    const float* __restrict__ a_src, const float* __restrict__ a_dst,
    float* __restrict__ h, float* __restrict__ as_out, float* __restrict__ ad_out,
    int N) {
  __shared__ float Wl[128 * 64];
  __shared__ float xs[4][128];
  const int t = threadIdx.x;
  for (int i = t; i < 128 * 64; i += 256) Wl[i] = W1[i];
  const int wave = t >> 6, lane = t & 63;
  const int row = blockIdx.x * 4 + wave;
  if (row < N) {
    xs[wave][lane]      = x[(size_t)row * 128 + lane];
    xs[wave][lane + 64] = x[(size_t)row * 128 + 64 + lane];
  }
  __syncthreads();
  if (row >= N) return;
  float sum = 0.f;
#pragma unroll
  for (int k = 0; k < 128; ++k) sum = fmaf(xs[wave][k], Wl[k * 64 + lane], sum);
  h[(size_t)row * 64 + lane] = sum;
  float va = sum * a_src[lane];
  float vd = sum * a_dst[lane];
#pragma unroll
  for (int off = 32; off > 0; off >>= 1) {
    va += __shfl_down(va, off, 64);
    vd += __shfl_down(vd, off, 64);
  }
  if (lane == 0) { as_out[row] = va; ad_out[row] = vd; }
}

// ---- GEMM2: h2 = relu(l1) @ W2 (64 -> 128), fused alpha_src/alpha_dst ----
__global__ __launch_bounds__(256) void gemm2_kernel(
    const float* __restrict__ l1, const float* __restrict__ W2,
    const float* __restrict__ a_src, const float* __restrict__ a_dst,
    float* __restrict__ h2, float* __restrict__ as_out, float* __restrict__ ad_out,
    int N) {
  __shared__ float Wl[64 * 128];
  __shared__ float xs[2][64];
  __shared__ float red[8];
  const int t = threadIdx.x;
  for (int i = t; i < 64 * 128; i += 256) Wl[i] = W2[i];
  const int rl = t >> 7;        // row within block: 0..1
  const int col = t & 127;      // 0..127
  const int row = blockIdx.x * 2 + rl;
  if (row < N && col < 64) xs[rl][col] = fmaxf(l1[(size_t)row * 64 + col], 0.f);
  __syncthreads();
  if (row < N) {
    float sum = 0.f;
#pragma unroll
    for (int k = 0; k < 64; ++k) sum = fmaf(xs[rl][k], Wl[k * 128 + col], sum);
    h2[(size_t)row * 128 + col] = sum;
    float va = sum * a_src[col];
    float vd = sum * a_dst[col];
#pragma unroll
    for (int off = 32; off > 0; off >>= 1) {
      va += __shfl_down(va, off, 64);
      vd += __shfl_down(vd, off, 64);
    }
    const int wv = t >> 6;  // 0..3
    if ((t & 63) == 0) { red[wv * 2] = va; red[wv * 2 + 1] = vd; }
  }
  __syncthreads();
  if (row < N && col == 0) {
    as_out[row] = red[rl * 4 + 0] + red[rl * 4 + 2];
    ad_out[row] = red[rl * 4 + 1] + red[rl * 4 + 3];
  }
}

// ---- per-edge segment max (atomic, flipped-bits) ----
__global__ __launch_bounds__(256) void edge_max_kernel(
    const int* __restrict__ srcs, const int* __restrict__ dsts, int E, int ET,
    const float* __restrict__ as1, const float* __restrict__ ad1,
    unsigned* __restrict__ mbits) {
  for (int i = blockIdx.x * blockDim.x + threadIdx.x; i < ET;
       i += gridDim.x * blockDim.x) {
    int s, d;
    if (i < E) { s = srcs[i]; d = dsts[i]; } else { s = d = i - E; }
    float e = as1[s] + ad1[d];
    e = e > 0.f ? e : NEG_SLOPE * e;
    atomicMax(mbits + d, flipf(e));
  }
}

// ---- per-edge exp-sum (atomic) ----
__global__ __launch_bounds__(256) void edge_sum_kernel(
    const int* __restrict__ srcs, const int* __restrict__ dsts, int E, int ET,
    const float* __restrict__ as1, const float* __restrict__ ad1,
    const unsigned* __restrict__ mbits, float* __restrict__ ssum) {
  for (int i = blockIdx.x * blockDim.x + threadIdx.x; i < ET;
       i += gridDim.x * blockDim.x) {
    int s, d;
    if (i < E) { s = srcs[i]; d = dsts[i]; } else { s = d = i - E; }
    float e = as1[s] + ad1[d];
    e = e > 0.f ? e : NEG_SLOPE * e;
    float ex = __expf(e - unflipf(mbits[d]));
    atomicAdd(ssum + d, ex);
  }
}

// ---- per-edge aggregation: out[dst] += alpha * h[src] (one wave per edge) ----
template <int F>
__global__ __launch_bounds__(256) void edge_agg_kernel(
    const int* __restrict__ srcs, const int* __restrict__ dsts, int E, int ET,
    const float* __restrict__ as1, const float* __restrict__ ad1,
    const unsigned* __restrict__ mbits, const float* __restrict__ ssum,
    const float* __restrict__ h, float* __restrict__ out) {
  const int lane = threadIdx.x & 63;
  const int wave = threadIdx.x >> 6;
  for (int i = blockIdx.x * 4 + wave; i < ET; i += gridDim.x * 4) {
    int s, d;
    if (i < E) { s = srcs[i]; d = dsts[i]; } else { s = d = i - E; }
    float e = as1[s] + ad1[d];
    e = e > 0.f ? e : NEG_SLOPE * e;
    float alpha = __expf(e - unflipf(mbits[d])) / (ssum[d] + GAT_EPS);
#pragma unroll
    for (int f = lane; f < F; f += 64)
      atomicAdd(out + (size_t)d * F + f, alpha * h[(size_t)s * F + f]);
  }
}

// ---- init an [N,F] buffer with a broadcast bias row ----
__global__ __launch_bounds__(256) void init_bias_kernel(
    float* __restrict__ out, const float* __restrict__ b, int total, int Fmask) {
  for (int i = blockIdx.x * blockDim.x + threadIdx.x; i < total;
       i += gridDim.x * blockDim.x)
    out[i] = b[i & Fmask];
}

extern "C" void kernel_launch(void* const* d_in, const int* in_sizes, int n_in,
                              void* d_out, int out_size, void* d_ws, size_t ws_size,
                              hipStream_t stream) {
  const float* x    = (const float*)d_in[0];
  const int*   ei   = (const int*)d_in[1];
  const float* W1   = (const float*)d_in[2];
  const float* a_s1 = (const float*)d_in[3];
  const float* a_d1 = (const float*)d_in[4];
  const float* b1   = (const float*)d_in[5];
  const float* W2   = (const float*)d_in[6];
  const float* a_s2 = (const float*)d_in[7];
  const float* a_d2 = (const float*)d_in[8];
  const float* b2   = (const float*)d_in[9];

  const int N  = in_sizes[0] / 128;
  const int E  = in_sizes[1] / 2;
  const int ET = E + N;
  const int* srcs = ei;
  const int* dsts = ei + E;

  // workspace layout (floats)
  float* ws    = (float*)d_ws;
  float* h1    = ws;                         // N*64
  float* l1out = h1 + (size_t)N * 64;        // N*64
  float* h2    = l1out + (size_t)N * 64;     // N*128
  float* as1   = h2 + (size_t)N * 128;       // N
  float* ad1   = as1 + N;                    // N
  float* as2   = ad1 + N;                    // N
  float* ad2   = as2 + N;                    // N
  float* zero0 = ad2 + N;                    // 4*N zero-init block:
  float* s1    = zero0;                      //   N
  unsigned* m1 = (unsigned*)(s1 + N);        //   N
  float* s2    = (float*)(m1 + N);           //   N
  unsigned* m2 = (unsigned*)(s2 + N);        //   N

  float* out = (float*)d_out;                // N*128

  // zero-init s1,m1,s2,m2 in one shot (0 is identity for both sum and flipped-max)
  hipMemsetAsync(zero0, 0, (size_t)4 * N * sizeof(float), stream);

  // ---- layer 1 ----
  gemm1_kernel<<<(N + 3) / 4, 256, 0, stream>>>(x, W1, a_s1, a_d1, h1, as1, ad1, N);
  init_bias_kernel<<<2048, 256, 0, stream>>>(l1out, b1, N * 64, 63);
  edge_max_kernel<<<2048, 256, 0, stream>>>(srcs, dsts, E, ET, as1, ad1, m1);
  edge_sum_kernel<<<2048, 256, 0, stream>>>(srcs, dsts, E, ET, as1, ad1, m1, s1);
  edge_agg_kernel<64><<<4096, 256, 0, stream>>>(srcs, dsts, E, ET, as1, ad1, m1, s1,
                                                h1, l1out);

  // ---- layer 2 (relu applied on load inside gemm2) ----
  gemm2_kernel<<<(N + 1) / 2, 256, 0, stream>>>(l1out, W2, a_s2, a_d2, h2, as2, ad2, N);
  init_bias_kernel<<<2048, 256, 0, stream>>>(out, b2, N * 128, 127);
  edge_max_kernel<<<2048, 256, 0, stream>>>(srcs, dsts, E, ET, as2, ad2, m2);
  edge_sum_kernel<<<2048, 256, 0, stream>>>(srcs, dsts, E, ET, as2, ad2, m2, s2);
  edge_agg_kernel<128><<<4096, 256, 0, stream>>>(srcs, dsts, E, ET, as2, ad2, m2, s2,
                                                 h2, out);
}

// Round 2
// 561.144 us; speedup vs baseline: 2.1111x; 2.1111x over previous
//
#include <hip/hip_runtime.h>

#define NEG_SLOPE 0.2f
#define GAT_EPS 1e-16f

// ---- GEMM1: h1 = x @ W1 (128 -> 64), fused alpha_src/alpha_dst ----
__global__ __launch_bounds__(256) void gemm1_kernel(
    const float* __restrict__ x, const float* __restrict__ W1,
    const float* __restrict__ a_src, const float* __restrict__ a_dst,
    float* __restrict__ h, float* __restrict__ as_out, float* __restrict__ ad_out,
    int N) {
  __shared__ float Wl[128 * 64];
  __shared__ float xs[4][128];
  const int t = threadIdx.x;
  for (int i = t; i < 128 * 64; i += 256) Wl[i] = W1[i];
  const int wave = t >> 6, lane = t & 63;
  const int row = blockIdx.x * 4 + wave;
  if (row < N) {
    xs[wave][lane]      = x[(size_t)row * 128 + lane];
    xs[wave][lane + 64] = x[(size_t)row * 128 + 64 + lane];
  }
  __syncthreads();
  if (row >= N) return;
  float sum = 0.f;
#pragma unroll
  for (int k = 0; k < 128; ++k) sum = fmaf(xs[wave][k], Wl[k * 64 + lane], sum);
  h[(size_t)row * 64 + lane] = sum;
  float va = sum * a_src[lane];
  float vd = sum * a_dst[lane];
#pragma unroll
  for (int off = 32; off > 0; off >>= 1) {
    va += __shfl_down(va, off, 64);
    vd += __shfl_down(vd, off, 64);
  }
  if (lane == 0) { as_out[row] = va; ad_out[row] = vd; }
}

// ---- GEMM2: h2 = relu(l1) @ W2 (64 -> 128), fused alpha_src/alpha_dst ----
__global__ __launch_bounds__(256) void gemm2_kernel(
    const float* __restrict__ l1, const float* __restrict__ W2,
    const float* __restrict__ a_src, const float* __restrict__ a_dst,
    float* __restrict__ h2, float* __restrict__ as_out, float* __restrict__ ad_out,
    int N) {
  __shared__ float Wl[64 * 128];
  __shared__ float xs[2][64];
  __shared__ float red[8];
  const int t = threadIdx.x;
  for (int i = t; i < 64 * 128; i += 256) Wl[i] = W2[i];
  const int rl = t >> 7;        // row within block: 0..1
  const int col = t & 127;      // 0..127
  const int row = blockIdx.x * 2 + rl;
  if (row < N && col < 64) xs[rl][col] = fmaxf(l1[(size_t)row * 64 + col], 0.f);
  __syncthreads();
  if (row < N) {
    float sum = 0.f;
#pragma unroll
    for (int k = 0; k < 64; ++k) sum = fmaf(xs[rl][k], Wl[k * 128 + col], sum);
    h2[(size_t)row * 128 + col] = sum;
    float va = sum * a_src[col];
    float vd = sum * a_dst[col];
#pragma unroll
    for (int off = 32; off > 0; off >>= 1) {
      va += __shfl_down(va, off, 64);
      vd += __shfl_down(vd, off, 64);
    }
    const int wv = t >> 6;  // 0..3
    if ((t & 63) == 0) { red[wv * 2] = va; red[wv * 2 + 1] = vd; }
  }
  __syncthreads();
  if (row < N && col == 0) {
    as_out[row] = red[rl * 4 + 0] + red[rl * 4 + 2];
    ad_out[row] = red[rl * 4 + 1] + red[rl * 4 + 3];
  }
}

// ---- CSR build: histogram of dst (self-loops appended implicitly) ----
__global__ __launch_bounds__(256) void hist_kernel(
    const int* __restrict__ dsts, int E, int ET, int* __restrict__ count) {
  for (int i = blockIdx.x * blockDim.x + threadIdx.x; i < ET;
       i += gridDim.x * blockDim.x) {
    int d = (i < E) ? dsts[i] : i - E;
    atomicAdd(count + d, 1);
  }
}

// ---- exclusive scan, 3-stage (N <= 256*256) ----
__global__ __launch_bounds__(256) void scan_blocks_kernel(
    const int* __restrict__ count, int* __restrict__ row_ptr,
    int* __restrict__ bsums, int N) {
  __shared__ int sd[256];
  const int t = threadIdx.x;
  const int i = blockIdx.x * 256 + t;
  int v = (i < N) ? count[i] : 0;
  sd[t] = v;
  __syncthreads();
  for (int off = 1; off < 256; off <<= 1) {
    int add = (t >= off) ? sd[t - off] : 0;
    __syncthreads();
    sd[t] += add;
    __syncthreads();
  }
  if (i < N) row_ptr[i] = sd[t] - v;   // exclusive, partial
  if (t == 255) bsums[blockIdx.x] = sd[255];
}

__global__ __launch_bounds__(256) void scan_top_kernel(int* __restrict__ bsums,
                                                       int nblk) {
  __shared__ int sd[256];
  const int t = threadIdx.x;
  int v = (t < nblk) ? bsums[t] : 0;
  sd[t] = v;
  __syncthreads();
  for (int off = 1; off < 256; off <<= 1) {
    int add = (t >= off) ? sd[t - off] : 0;
    __syncthreads();
    sd[t] += add;
    __syncthreads();
  }
  if (t < nblk) bsums[t] = sd[t] - v;  // exclusive
}

__global__ __launch_bounds__(256) void scan_add_kernel(
    int* __restrict__ row_ptr, const int* __restrict__ bsums,
    int* __restrict__ next, int N, int ET) {
  const int i = blockIdx.x * 256 + threadIdx.x;
  if (i < N) {
    int v = row_ptr[i] + bsums[blockIdx.x];
    row_ptr[i] = v;
    next[i] = v;
  }
  if (i == 0) row_ptr[N] = ET;
}

// ---- scatter edges into dst-sorted order (only src is needed) ----
__global__ __launch_bounds__(256) void scatter_kernel(
    const int* __restrict__ srcs, const int* __restrict__ dsts, int E, int ET,
    int* __restrict__ next, int* __restrict__ ssrc) {
  for (int i = blockIdx.x * blockDim.x + threadIdx.x; i < ET;
       i += gridDim.x * blockDim.x) {
    int s, d;
    if (i < E) { s = srcs[i]; d = dsts[i]; } else { s = d = i - E; }
    int pos = atomicAdd(next + d, 1);
    ssrc[pos] = s;
  }
}

// ---- fused per-node GAT aggregation: one wave per node ----
template <int F>
__global__ __launch_bounds__(256) void node_agg_kernel(
    const int* __restrict__ row_ptr, const int* __restrict__ ssrc,
    const float* __restrict__ as, const float* __restrict__ ad_arr,
    const float* __restrict__ h, const float* __restrict__ bias,
    float* __restrict__ out, int N) {
  const int lane = threadIdx.x & 63;
  const int wave = threadIdx.x >> 6;
  const int node = blockIdx.x * 4 + wave;
  if (node >= N) return;
  const int beg = row_ptr[node], end = row_ptr[node + 1];
  const float ad = ad_arr[node];
  // pass A: segment max
  float m = -3.4e38f;
  for (int j = beg + lane; j < end; j += 64) {
    float e = as[ssrc[j]] + ad;
    e = e > 0.f ? e : NEG_SLOPE * e;
    m = fmaxf(m, e);
  }
#pragma unroll
  for (int off = 32; off > 0; off >>= 1) m = fmaxf(m, __shfl_xor(m, off, 64));
  // pass B: exp-sum
  float S = 0.f;
  for (int j = beg + lane; j < end; j += 64) {
    float e = as[ssrc[j]] + ad;
    e = e > 0.f ? e : NEG_SLOPE * e;
    S += __expf(e - m);
  }
#pragma unroll
  for (int off = 32; off > 0; off >>= 1) S += __shfl_xor(S, off, 64);
  const float inv = 1.f / (S + GAT_EPS);
  // pass C: weighted feature aggregation (lanes over features)
  float acc[F / 64];
#pragma unroll
  for (int c = 0; c < F / 64; ++c) acc[c] = 0.f;
  for (int j = beg; j < end; ++j) {
    int s = ssrc[j];  // wave-uniform broadcast load
    float e = as[s] + ad;
    e = e > 0.f ? e : NEG_SLOPE * e;
    float alpha = __expf(e - m) * inv;
#pragma unroll
    for (int c = 0; c < F / 64; ++c)
      acc[c] = fmaf(alpha, h[(size_t)s * F + c * 64 + lane], acc[c]);
  }
#pragma unroll
  for (int c = 0; c < F / 64; ++c)
    out[(size_t)node * F + c * 64 + lane] = acc[c] + bias[c * 64 + lane];
}

extern "C" void kernel_launch(void* const* d_in, const int* in_sizes, int n_in,
                              void* d_out, int out_size, void* d_ws, size_t ws_size,
                              hipStream_t stream) {
  const float* x    = (const float*)d_in[0];
  const int*   ei   = (const int*)d_in[1];
  const float* W1   = (const float*)d_in[2];
  const float* a_s1 = (const float*)d_in[3];
  const float* a_d1 = (const float*)d_in[4];
  const float* b1   = (const float*)d_in[5];
  const float* W2   = (const float*)d_in[6];
  const float* a_s2 = (const float*)d_in[7];
  const float* a_d2 = (const float*)d_in[8];
  const float* b2   = (const float*)d_in[9];

  const int N  = in_sizes[0] / 128;
  const int E  = in_sizes[1] / 2;
  const int ET = E + N;
  const int* srcs = ei;
  const int* dsts = ei + E;
  const int nblk = (N + 255) / 256;

  // workspace layout
  float* ws    = (float*)d_ws;
  float* h1    = ws;                          // N*64
  float* l1out = h1 + (size_t)N * 64;         // N*64
  float* h2    = l1out + (size_t)N * 64;      // N*128
  float* as1   = h2 + (size_t)N * 128;        // N
  float* ad1   = as1 + N;                     // N
  float* as2   = ad1 + N;                     // N
  float* ad2   = as2 + N;                     // N
  int* row_ptr = (int*)(ad2 + N);             // N+1
  int* next    = row_ptr + (N + 1);           // N (aliases histogram count)
  int* ssrc    = next + N;                    // ET
  int* bsums   = ssrc + ET;                   // nblk
  int* count   = next;                        // alias: dead after scan

  float* out = (float*)d_out;  // N*128

  // ---- build dst-sorted CSR (same for both layers) ----
  hipMemsetAsync(count, 0, (size_t)N * sizeof(int), stream);
  hist_kernel<<<2048, 256, 0, stream>>>(dsts, E, ET, count);
  scan_blocks_kernel<<<nblk, 256, 0, stream>>>(count, row_ptr, bsums, N);
  scan_top_kernel<<<1, 256, 0, stream>>>(bsums, nblk);
  scan_add_kernel<<<nblk, 256, 0, stream>>>(row_ptr, bsums, next, N, ET);
  scatter_kernel<<<2048, 256, 0, stream>>>(srcs, dsts, E, ET, next, ssrc);

  // ---- layer 1 ----
  gemm1_kernel<<<(N + 3) / 4, 256, 0, stream>>>(x, W1, a_s1, a_d1, h1, as1, ad1, N);
  node_agg_kernel<64><<<(N + 3) / 4, 256, 0, stream>>>(row_ptr, ssrc, as1, ad1,
                                                       h1, b1, l1out, N);

  // ---- layer 2 (relu applied on load inside gemm2) ----
  gemm2_kernel<<<(N + 1) / 2, 256, 0, stream>>>(l1out, W2, a_s2, a_d2, h2, as2, ad2, N);
  node_agg_kernel<128><<<(N + 3) / 4, 256, 0, stream>>>(row_ptr, ssrc, as2, ad2,
                                                        h2, b2, out, N);
}

// Round 3
// 497.324 us; speedup vs baseline: 2.3820x; 1.1283x over previous
//
#include <hip/hip_runtime.h>
#include <hip/hip_fp16.h>

#define NEG_SLOPE 0.2f
#define GAT_EPS 1e-16f

// ---- prep: w2as = W2 @ a_src2, w2ad = W2 @ a_dst2 (W2 is [64,128] row-major) ----
__global__ __launch_bounds__(128) void prep_kernel(
    const float* __restrict__ W2, const float* __restrict__ a_s2,
    const float* __restrict__ a_d2, float* __restrict__ w2as,
    float* __restrict__ w2ad) {
  const int t = threadIdx.x;  // 128 threads
  const int c = t & 63;
  const float* av = (t < 64) ? a_s2 : a_d2;
  float s = 0.f;
  for (int j = 0; j < 128; ++j) s = fmaf(W2[c * 128 + j], av[j], s);
  if (t < 64) w2as[c] = s; else w2ad[c] = s;
}

// ---- GEMM1: h1 = x @ W1 (128 -> 64) as fp16, fused alpha_src/alpha_dst ----
__global__ __launch_bounds__(256) void gemm1_kernel(
    const float* __restrict__ x, const float* __restrict__ W1,
    const float* __restrict__ a_src, const float* __restrict__ a_dst,
    __half* __restrict__ h16, float* __restrict__ as_out,
    float* __restrict__ ad_out, int N) {
  __shared__ float Wl[128 * 64];
  __shared__ float xs[4][128];
  const int t = threadIdx.x;
  for (int i = t; i < 128 * 64; i += 256) Wl[i] = W1[i];
  const int wave = t >> 6, lane = t & 63;
  const int row = blockIdx.x * 4 + wave;
  if (row < N) {
    xs[wave][lane]      = x[(size_t)row * 128 + lane];
    xs[wave][lane + 64] = x[(size_t)row * 128 + 64 + lane];
  }
  __syncthreads();
  if (row >= N) return;
  float sum = 0.f;
#pragma unroll
  for (int k = 0; k < 128; ++k) sum = fmaf(xs[wave][k], Wl[k * 64 + lane], sum);
  h16[(size_t)row * 64 + lane] = __float2half(sum);
  float va = sum * a_src[lane];
  float vd = sum * a_dst[lane];
#pragma unroll
  for (int off = 32; off > 0; off >>= 1) {
    va += __shfl_down(va, off, 64);
    vd += __shfl_down(vd, off, 64);
  }
  if (lane == 0) { as_out[row] = va; ad_out[row] = vd; }
}

// ---- CSR build: histogram of dst (self-loops appended implicitly) ----
__global__ __launch_bounds__(256) void hist_kernel(
    const int* __restrict__ dsts, int E, int ET, int* __restrict__ count) {
  for (int i = blockIdx.x * blockDim.x + threadIdx.x; i < ET;
       i += gridDim.x * blockDim.x) {
    int d = (i < E) ? dsts[i] : i - E;
    atomicAdd(count + d, 1);
  }
}

__global__ __launch_bounds__(256) void scan_blocks_kernel(
    const int* __restrict__ count, int* __restrict__ row_ptr,
    int* __restrict__ bsums, int N) {
  __shared__ int sd[256];
  const int t = threadIdx.x;
  const int i = blockIdx.x * 256 + t;
  int v = (i < N) ? count[i] : 0;
  sd[t] = v;
  __syncthreads();
  for (int off = 1; off < 256; off <<= 1) {
    int add = (t >= off) ? sd[t - off] : 0;
    __syncthreads();
    sd[t] += add;
    __syncthreads();
  }
  if (i < N) row_ptr[i] = sd[t] - v;  // exclusive, partial
  if (t == 255) bsums[blockIdx.x] = sd[255];
}

__global__ __launch_bounds__(256) void scan_top_kernel(int* __restrict__ bsums,
                                                       int nblk) {
  __shared__ int sd[256];
  const int t = threadIdx.x;
  int v = (t < nblk) ? bsums[t] : 0;
  sd[t] = v;
  __syncthreads();
  for (int off = 1; off < 256; off <<= 1) {
    int add = (t >= off) ? sd[t - off] : 0;
    __syncthreads();
    sd[t] += add;
    __syncthreads();
  }
  if (t < nblk) bsums[t] = sd[t] - v;  // exclusive
}

__global__ __launch_bounds__(256) void scan_add_kernel(
    int* __restrict__ row_ptr, const int* __restrict__ bsums,
    int* __restrict__ next, int N, int ET) {
  const int i = blockIdx.x * 256 + threadIdx.x;
  if (i < N) {
    int v = row_ptr[i] + bsums[blockIdx.x];
    row_ptr[i] = v;
    next[i] = v;
  }
  if (i == 0) row_ptr[N] = ET;
}

__global__ __launch_bounds__(256) void scatter_kernel(
    const int* __restrict__ srcs, const int* __restrict__ dsts, int E, int ET,
    int* __restrict__ next, int* __restrict__ ssrc) {
  for (int i = blockIdx.x * blockDim.x + threadIdx.x; i < ET;
       i += gridDim.x * blockDim.x) {
    int s, d;
    if (i < E) { s = srcs[i]; d = dsts[i]; } else { s = d = i - E; }
    int pos = atomicAdd(next + d, 1);
    ssrc[pos] = s;
  }
}

// ---- layer-1 fused aggregation: one wave per node, single pass ----
// out: rl1 = fp16(relu(agg + b1)); as2/ad2 = rl1 . (W2@a_{src,dst}2)
__global__ __launch_bounds__(256) void node_agg1_kernel(
    const int* __restrict__ row_ptr, const int* __restrict__ ssrc,
    const float* __restrict__ as, const float* __restrict__ ad_arr,
    const __half* __restrict__ h16, const float* __restrict__ b1,
    const float* __restrict__ w2as, const float* __restrict__ w2ad,
    __half* __restrict__ rl1, float* __restrict__ as2,
    float* __restrict__ ad2, int N) {
  const int lane = threadIdx.x & 63;
  const int wave = threadIdx.x >> 6;
  const int node = blockIdx.x * 4 + wave;
  if (node >= N) return;
  const int beg = row_ptr[node], end = row_ptr[node + 1];
  const float ad = ad_arr[node];
  float S = 0.f, acc = 0.f;
  for (int j = beg; j < end; ++j) {
    int s = __builtin_amdgcn_readfirstlane(ssrc[j]);
    float e = as[s] + ad;
    e = e > 0.f ? e : NEG_SLOPE * e;
    float p = __expf(e);
    S += p;
    acc = fmaf(p, __half2float(h16[(size_t)s * 64 + lane]), acc);
  }
  float v = acc / (S + GAT_EPS) + b1[lane];
  float r = fmaxf(v, 0.f);
  rl1[(size_t)node * 64 + lane] = __float2half(r);
  float va = r * w2as[lane];
  float vd = r * w2ad[lane];
#pragma unroll
  for (int off = 32; off > 0; off >>= 1) {
    va += __shfl_down(va, off, 64);
    vd += __shfl_down(vd, off, 64);
  }
  if (lane == 0) { as2[node] = va; ad2[node] = vd; }
}

// ---- layer-2 fused aggregation in 64-dim space (W2 commuted out) ----
__global__ __launch_bounds__(256) void node_agg2_kernel(
    const int* __restrict__ row_ptr, const int* __restrict__ ssrc,
    const float* __restrict__ as, const float* __restrict__ ad_arr,
    const __half* __restrict__ rl1, float* __restrict__ agg2, int N) {
  const int lane = threadIdx.x & 63;
  const int wave = threadIdx.x >> 6;
  const int node = blockIdx.x * 4 + wave;
  if (node >= N) return;
  const int beg = row_ptr[node], end = row_ptr[node + 1];
  const float ad = ad_arr[node];
  float S = 0.f, acc = 0.f;
  for (int j = beg; j < end; ++j) {
    int s = __builtin_amdgcn_readfirstlane(ssrc[j]);
    float e = as[s] + ad;
    e = e > 0.f ? e : NEG_SLOPE * e;
    float p = __expf(e);
    S += p;
    acc = fmaf(p, __half2float(rl1[(size_t)s * 64 + lane]), acc);
  }
  agg2[(size_t)node * 64 + lane] = acc / (S + GAT_EPS);
}

// ---- final GEMM: out = agg2 @ W2 + b2 (64 -> 128) ----
__global__ __launch_bounds__(256) void gemm_out_kernel(
    const float* __restrict__ agg2, const float* __restrict__ W2,
    const float* __restrict__ b2, float* __restrict__ out, int N) {
  __shared__ float Wl[64 * 128];
  __shared__ float xs[2][64];
  const int t = threadIdx.x;
  for (int i = t; i < 64 * 128; i += 256) Wl[i] = W2[i];
  const int rl = t >> 7;   // row within block
  const int col = t & 127;
  const int row = blockIdx.x * 2 + rl;
  if (row < N && col < 64) xs[rl][col] = agg2[(size_t)row * 64 + col];
  __syncthreads();
  if (row >= N) return;
  float sum = b2[col];
#pragma unroll
  for (int k = 0; k < 64; ++k) sum = fmaf(xs[rl][k], Wl[k * 128 + col], sum);
  out[(size_t)row * 128 + col] = sum;
}

extern "C" void kernel_launch(void* const* d_in, const int* in_sizes, int n_in,
                              void* d_out, int out_size, void* d_ws, size_t ws_size,
                              hipStream_t stream) {
  const float* x    = (const float*)d_in[0];
  const int*   ei   = (const int*)d_in[1];
  const float* W1   = (const float*)d_in[2];
  const float* a_s1 = (const float*)d_in[3];
  const float* a_d1 = (const float*)d_in[4];
  const float* b1   = (const float*)d_in[5];
  const float* W2   = (const float*)d_in[6];
  const float* a_s2 = (const float*)d_in[7];
  const float* a_d2 = (const float*)d_in[8];
  const float* b2   = (const float*)d_in[9];

  const int N  = in_sizes[0] / 128;
  const int E  = in_sizes[1] / 2;
  const int ET = E + N;
  const int* srcs = ei;
  const int* dsts = ei + E;
  const int nblk = (N + 255) / 256;

  // workspace layout
  char* w = (char*)d_ws;
  __half* h16  = (__half*)w;            w += (size_t)N * 64 * 2;
  __half* rl1  = (__half*)w;            w += (size_t)N * 64 * 2;
  float* agg2  = (float*)w;             w += (size_t)N * 64 * 4;
  float* as1   = (float*)w;             w += (size_t)N * 4;
  float* ad1   = (float*)w;             w += (size_t)N * 4;
  float* as2   = (float*)w;             w += (size_t)N * 4;
  float* ad2   = (float*)w;             w += (size_t)N * 4;
  float* w2as  = (float*)w;             w += 64 * 4;
  float* w2ad  = (float*)w;             w += 64 * 4;
  int* row_ptr = (int*)w;               w += (size_t)(N + 1) * 4;
  int* next    = (int*)w;               w += (size_t)N * 4;
  int* ssrc    = (int*)w;               w += (size_t)ET * 4;
  int* bsums   = (int*)w;               w += (size_t)nblk * 4;
  int* count   = next;  // alias: histogram is dead after scan

  float* out = (float*)d_out;  // N*128

  // ---- build dst-sorted CSR ----
  hipMemsetAsync(count, 0, (size_t)N * sizeof(int), stream);
  hist_kernel<<<2048, 256, 0, stream>>>(dsts, E, ET, count);
  scan_blocks_kernel<<<nblk, 256, 0, stream>>>(count, row_ptr, bsums, N);
  scan_top_kernel<<<1, 256, 0, stream>>>(bsums, nblk);
  scan_add_kernel<<<nblk, 256, 0, stream>>>(row_ptr, bsums, next, N, ET);
  scatter_kernel<<<2048, 256, 0, stream>>>(srcs, dsts, E, ET, next, ssrc);

  // ---- weights prep + layer 1 ----
  prep_kernel<<<1, 128, 0, stream>>>(W2, a_s2, a_d2, w2as, w2ad);
  gemm1_kernel<<<(N + 3) / 4, 256, 0, stream>>>(x, W1, a_s1, a_d1, h16, as1, ad1, N);
  node_agg1_kernel<<<(N + 3) / 4, 256, 0, stream>>>(row_ptr, ssrc, as1, ad1, h16,
                                                    b1, w2as, w2ad, rl1, as2, ad2, N);

  // ---- layer 2 (aggregation in 64-dim, then W2) ----
  node_agg2_kernel<<<(N + 3) / 4, 256, 0, stream>>>(row_ptr, ssrc, as2, ad2, rl1,
                                                    agg2, N);
  gemm_out_kernel<<<(N + 1) / 2, 256, 0, stream>>>(agg2, W2, b2, out, N);
}

// Round 4
// 352.493 us; speedup vs baseline: 3.3608x; 1.4109x over previous
//
#include <hip/hip_runtime.h>
#include <hip/hip_fp16.h>

#define NEG_SLOPE 0.2f
#define GAT_EPS 1e-16f

// ---- prep: w2as = W2 @ a_src2, w2ad = W2 @ a_dst2 (W2 is [64,128] row-major) ----
__global__ __launch_bounds__(128) void prep_kernel(
    const float* __restrict__ W2, const float* __restrict__ a_s2,
    const float* __restrict__ a_d2, float* __restrict__ w2as,
    float* __restrict__ w2ad) {
  const int t = threadIdx.x;  // 128 threads
  const int c = t & 63;
  const float* av = (t < 64) ? a_s2 : a_d2;
  float s = 0.f;
  for (int j = 0; j < 128; ++j) s = fmaf(W2[c * 128 + j], av[j], s);
  if (t < 64) w2as[c] = s; else w2ad[c] = s;
}

// ---- GEMM1: h1 = x @ W1 (128 -> 64) as fp16, fused alpha_src/alpha_dst ----
// 16 rows/block, 4 rows/wave.
__global__ __launch_bounds__(256) void gemm1_kernel(
    const float* __restrict__ x, const float* __restrict__ W1,
    const float* __restrict__ a_src, const float* __restrict__ a_dst,
    __half* __restrict__ h16, float* __restrict__ as_out,
    float* __restrict__ ad_out, int N) {
  __shared__ float Wl[128 * 64];   // 32 KB
  __shared__ float xs[16][128];    // 8 KB
  const int t = threadIdx.x;
  const int base = blockIdx.x * 16;
  // cooperative loads (float4)
  {
    const float4* Wv = (const float4*)W1;
    float4* Wd = (float4*)Wl;
    for (int i = t; i < 128 * 64 / 4; i += 256) Wd[i] = Wv[i];
    const float4* Xv = (const float4*)(x + (size_t)base * 128);
    float4* Xd = (float4*)xs;
    int lim = (base + 16 <= N) ? 16 * 128 / 4 : ((N - base) * 128) / 4;
    for (int i = t; i < lim; i += 256) Xd[i] = Xv[i];
  }
  __syncthreads();
  const int wave = t >> 6, lane = t & 63;
  const int wr = wave * 4;
  float acc[4] = {0.f, 0.f, 0.f, 0.f};
  for (int k = 0; k < 128; ++k) {
    float wv = Wl[k * 64 + lane];
#pragma unroll
    for (int r = 0; r < 4; ++r) acc[r] = fmaf(xs[wr + r][k], wv, acc[r]);
  }
  const float asl = a_src[lane], adl = a_dst[lane];
#pragma unroll
  for (int r = 0; r < 4; ++r) {
    const int row = base + wr + r;
    if (row >= N) break;
    h16[(size_t)row * 64 + lane] = __float2half(acc[r]);
    float va = acc[r] * asl;
    float vd = acc[r] * adl;
#pragma unroll
    for (int off = 32; off > 0; off >>= 1) {
      va += __shfl_down(va, off, 64);
      vd += __shfl_down(vd, off, 64);
    }
    if (lane == 0) { as_out[row] = va; ad_out[row] = vd; }
  }
}

// ---- CSR build: histogram of dst (self-loops appended implicitly) ----
__global__ __launch_bounds__(256) void hist_kernel(
    const int* __restrict__ dsts, int E, int ET, int* __restrict__ count) {
  for (int i = blockIdx.x * blockDim.x + threadIdx.x; i < ET;
       i += gridDim.x * blockDim.x) {
    int d = (i < E) ? dsts[i] : i - E;
    atomicAdd(count + d, 1);
  }
}

__global__ __launch_bounds__(256) void scan_blocks_kernel(
    const int* __restrict__ count, int* __restrict__ row_ptr,
    int* __restrict__ bsums, int N) {
  __shared__ int sd[256];
  const int t = threadIdx.x;
  const int i = blockIdx.x * 256 + t;
  int v = (i < N) ? count[i] : 0;
  sd[t] = v;
  __syncthreads();
  for (int off = 1; off < 256; off <<= 1) {
    int add = (t >= off) ? sd[t - off] : 0;
    __syncthreads();
    sd[t] += add;
    __syncthreads();
  }
  if (i < N) row_ptr[i] = sd[t] - v;  // exclusive, partial
  if (t == 255) bsums[blockIdx.x] = sd[255];
}

__global__ __launch_bounds__(256) void scan_top_kernel(int* __restrict__ bsums,
                                                       int nblk) {
  __shared__ int sd[256];
  const int t = threadIdx.x;
  int v = (t < nblk) ? bsums[t] : 0;
  sd[t] = v;
  __syncthreads();
  for (int off = 1; off < 256; off <<= 1) {
    int add = (t >= off) ? sd[t - off] : 0;
    __syncthreads();
    sd[t] += add;
    __syncthreads();
  }
  if (t < nblk) bsums[t] = sd[t] - v;  // exclusive
}

__global__ __launch_bounds__(256) void scan_add_kernel(
    int* __restrict__ row_ptr, const int* __restrict__ bsums,
    int* __restrict__ next, int N, int ET) {
  const int i = blockIdx.x * 256 + threadIdx.x;
  if (i < N) {
    int v = row_ptr[i] + bsums[blockIdx.x];
    row_ptr[i] = v;
    next[i] = v;
  }
  if (i == 0) row_ptr[N] = ET;
}

// ---- scatter edges into dst-sorted order + fused layer-1 edge weights ----
__global__ __launch_bounds__(256) void scatter_pe1_kernel(
    const int* __restrict__ srcs, const int* __restrict__ dsts, int E, int ET,
    int* __restrict__ next, const float* __restrict__ as1,
    const float* __restrict__ ad1, int* __restrict__ ssrc,
    int* __restrict__ sdst, float* __restrict__ pe) {
  for (int i = blockIdx.x * blockDim.x + threadIdx.x; i < ET;
       i += gridDim.x * blockDim.x) {
    int s, d;
    if (i < E) { s = srcs[i]; d = dsts[i]; } else { s = d = i - E; }
    int pos = atomicAdd(next + d, 1);
    ssrc[pos] = s;
    sdst[pos] = d;
    float e = as1[s] + ad1[d];
    e = e > 0.f ? e : NEG_SLOPE * e;
    pe[pos] = __expf(e);
  }
}

// ---- layer-2 edge weights (sorted order) ----
__global__ __launch_bounds__(256) void edge_p2_kernel(
    const int* __restrict__ ssrc, const int* __restrict__ sdst, int ET,
    const float* __restrict__ as2, const float* __restrict__ ad2,
    float* __restrict__ pe) {
  for (int i = blockIdx.x * blockDim.x + threadIdx.x; i < ET;
       i += gridDim.x * blockDim.x) {
    float e = as2[ssrc[i]] + ad2[sdst[i]];
    e = e > 0.f ? e : NEG_SLOPE * e;
    pe[i] = __expf(e);
  }
}

// ---- fused per-node aggregation: one wave/node, 2 edges per iter (half-wave
// split), packed __half2 gathers, 2x unroll -> 4 gathers in flight ----
// LAYER: 1 -> epilogue writes rl1 (fp16 relu) + as2/ad2;  2 -> writes agg2 (f32)
template <int LAYER>
__global__ __launch_bounds__(256) void node_agg_kernel(
    const int* __restrict__ row_ptr, const int* __restrict__ ssrc,
    const float* __restrict__ pe, const __half* __restrict__ hsrc,
    const float* __restrict__ b1, const float* __restrict__ w2as,
    const float* __restrict__ w2ad, __half* __restrict__ rl1,
    float* __restrict__ as2, float* __restrict__ ad2,
    float* __restrict__ agg2, int N) {
  const int lane = threadIdx.x & 63;
  const int half = lane >> 5;       // 0: even edges, 1: odd edges
  const int hl = lane & 31;         // feature pair index
  const int node = blockIdx.x * 4 + (threadIdx.x >> 6);
  if (node >= N) return;
  const int beg = row_ptr[node], end = row_ptr[node + 1];

  float acc0 = 0.f, acc1 = 0.f, acc0b = 0.f, acc1b = 0.f, Sl = 0.f, Slb = 0.f;
  int j = beg + half;
  for (; j + 2 < end; j += 4) {
    int s0 = ssrc[j];
    int s1 = ssrc[j + 2];
    float p0 = pe[j];
    float p1 = pe[j + 2];
    float2 f0 = __half22float2(*(const __half2*)(hsrc + (size_t)s0 * 64 + 2 * hl));
    float2 f1 = __half22float2(*(const __half2*)(hsrc + (size_t)s1 * 64 + 2 * hl));
    acc0  = fmaf(p0, f0.x, acc0);  acc1  = fmaf(p0, f0.y, acc1);  Sl  += p0;
    acc0b = fmaf(p1, f1.x, acc0b); acc1b = fmaf(p1, f1.y, acc1b); Slb += p1;
  }
  if (j < end) {
    int s0 = ssrc[j];
    float p0 = pe[j];
    float2 f0 = __half22float2(*(const __half2*)(hsrc + (size_t)s0 * 64 + 2 * hl));
    acc0 = fmaf(p0, f0.x, acc0); acc1 = fmaf(p0, f0.y, acc1); Sl += p0;
  }
  acc0 += acc0b; acc1 += acc1b; Sl += Slb;
  // combine the two half-wave edge streams (feature pair identical across halves)
  acc0 += __shfl_xor(acc0, 32, 64);
  acc1 += __shfl_xor(acc1, 32, 64);
  Sl   += __shfl_xor(Sl, 32, 64);
  const float inv = 1.f / (Sl + GAT_EPS);

  if (LAYER == 1) {
    float2 bb = ((const float2*)b1)[hl];
    float r0 = fmaxf(fmaf(acc0, inv, bb.x), 0.f);
    float r1 = fmaxf(fmaf(acc1, inv, bb.y), 0.f);
    if (half == 0)
      *(__half2*)(rl1 + (size_t)node * 64 + 2 * hl) = __floats2half2_rn(r0, r1);
    float2 was = ((const float2*)w2as)[hl];
    float2 wad = ((const float2*)w2ad)[hl];
    float va = fmaf(r0, was.x, r1 * was.y);
    float vd = fmaf(r0, wad.x, r1 * wad.y);
#pragma unroll
    for (int off = 16; off > 0; off >>= 1) {
      va += __shfl_xor(va, off, 64);
      vd += __shfl_xor(vd, off, 64);
    }
    if (lane == 0) { as2[node] = va; ad2[node] = vd; }
  } else {
    if (half == 0) {
      float2 o; o.x = acc0 * inv; o.y = acc1 * inv;
      *(float2*)(agg2 + (size_t)node * 64 + 2 * hl) = o;
    }
  }
}

// ---- final GEMM: out = agg2 @ W2 + b2 (64 -> 128), 8 rows/block ----
__global__ __launch_bounds__(256) void gemm_out_kernel(
    const float* __restrict__ agg2, const float* __restrict__ W2,
    const float* __restrict__ b2, float* __restrict__ out, int N) {
  __shared__ float Wl[64 * 128];  // 32 KB
  __shared__ float xs[8][64];     // 2 KB
  const int t = threadIdx.x;
  const int base = blockIdx.x * 8;
  {
    const float4* Wv = (const float4*)W2;
    float4* Wd = (float4*)Wl;
    for (int i = t; i < 64 * 128 / 4; i += 256) Wd[i] = Wv[i];
    const float4* Xv = (const float4*)(agg2 + (size_t)base * 64);
    float4* Xd = (float4*)xs;
    int lim = (base + 8 <= N) ? 8 * 64 / 4 : ((N - base) * 64) / 4;
    for (int i = t; i < lim; i += 256) Xd[i] = Xv[i];
  }
  __syncthreads();
  const int wave = t >> 6, lane = t & 63;
  const int rg = wave >> 1;              // row group 0..1 (4 rows each)
  const int col = (wave & 1) * 64 + lane;  // 0..127
  float acc[4];
  const float bc = b2[col];
#pragma unroll
  for (int r = 0; r < 4; ++r) acc[r] = bc;
  for (int k = 0; k < 64; ++k) {
    float wv = Wl[k * 128 + col];
#pragma unroll
    for (int r = 0; r < 4; ++r) acc[r] = fmaf(xs[rg * 4 + r][k], wv, acc[r]);
  }
#pragma unroll
  for (int r = 0; r < 4; ++r) {
    const int row = base + rg * 4 + r;
    if (row < N) out[(size_t)row * 128 + col] = acc[r];
  }
}

extern "C" void kernel_launch(void* const* d_in, const int* in_sizes, int n_in,
                              void* d_out, int out_size, void* d_ws, size_t ws_size,
                              hipStream_t stream) {
  const float* x    = (const float*)d_in[0];
  const int*   ei   = (const int*)d_in[1];
  const float* W1   = (const float*)d_in[2];
  const float* a_s1 = (const float*)d_in[3];
  const float* a_d1 = (const float*)d_in[4];
  const float* b1   = (const float*)d_in[5];
  const float* W2   = (const float*)d_in[6];
  const float* a_s2 = (const float*)d_in[7];
  const float* a_d2 = (const float*)d_in[8];
  const float* b2   = (const float*)d_in[9];

  const int N  = in_sizes[0] / 128;
  const int E  = in_sizes[1] / 2;
  const int ET = E + N;
  const int* srcs = ei;
  const int* dsts = ei + E;
  const int nblk = (N + 255) / 256;

  // workspace layout
  char* w = (char*)d_ws;
  __half* h16  = (__half*)w;            w += (size_t)N * 64 * 2;
  __half* rl1  = (__half*)w;            w += (size_t)N * 64 * 2;
  float* agg2  = (float*)w;             w += (size_t)N * 64 * 4;
  float* as1   = (float*)w;             w += (size_t)N * 4;
  float* ad1   = (float*)w;             w += (size_t)N * 4;
  float* as2   = (float*)w;             w += (size_t)N * 4;
  float* ad2   = (float*)w;             w += (size_t)N * 4;
  float* w2as  = (float*)w;             w += 64 * 4;
  float* w2ad  = (float*)w;             w += 64 * 4;
  int* row_ptr = (int*)w;               w += (size_t)(N + 1) * 4;
  int* next    = (int*)w;               w += (size_t)N * 4;
  int* ssrc    = (int*)w;               w += (size_t)ET * 4;
  int* sdst    = (int*)w;               w += (size_t)ET * 4;
  float* pe    = (float*)w;             w += (size_t)ET * 4;
  int* bsums   = (int*)w;               w += (size_t)nblk * 4;
  int* count   = next;  // alias: histogram is dead after scan

  float* out = (float*)d_out;  // N*128

  // ---- build CSR skeleton (independent of features) ----
  hipMemsetAsync(count, 0, (size_t)N * sizeof(int), stream);
  hist_kernel<<<2048, 256, 0, stream>>>(dsts, E, ET, count);
  scan_blocks_kernel<<<nblk, 256, 0, stream>>>(count, row_ptr, bsums, N);
  scan_top_kernel<<<1, 256, 0, stream>>>(bsums, nblk);
  scan_add_kernel<<<nblk, 256, 0, stream>>>(row_ptr, bsums, next, N, ET);

  // ---- weights prep + layer-1 features ----
  prep_kernel<<<1, 128, 0, stream>>>(W2, a_s2, a_d2, w2as, w2ad);
  gemm1_kernel<<<(N + 15) / 16, 256, 0, stream>>>(x, W1, a_s1, a_d1, h16, as1,
                                                  ad1, N);
  // ---- scatter (sorted adjacency) + layer-1 edge weights ----
  scatter_pe1_kernel<<<2048, 256, 0, stream>>>(srcs, dsts, E, ET, next, as1, ad1,
                                               ssrc, sdst, pe);
  // ---- layer-1 aggregation ----
  node_agg_kernel<1><<<(N + 3) / 4, 256, 0, stream>>>(
      row_ptr, ssrc, pe, h16, b1, w2as, w2ad, rl1, as2, ad2, (float*)nullptr, N);
  // ---- layer-2 edge weights + aggregation (64-dim, W2 commuted out) ----
  edge_p2_kernel<<<2048, 256, 0, stream>>>(ssrc, sdst, ET, as2, ad2, pe);
  node_agg_kernel<2><<<(N + 3) / 4, 256, 0, stream>>>(
      row_ptr, ssrc, pe, rl1, b1, w2as, w2ad, (( __half*)nullptr), as2, ad2,
      agg2, N);
  // ---- final GEMM ----
  gemm_out_kernel<<<(N + 7) / 8, 256, 0, stream>>>(agg2, W2, b2, out, N);
}